// Round 5
// baseline (858.803 us; speedup 1.0000x reference)
//
#include <hip/hip_runtime.h>
#include <stdint.h>

// Problem constants
#define B_   2
#define SQ   2048
#define H    1024
#define NH   16
#define HN   64
#define T_TOK 4096          // sq*b tokens
#define N3H  3072           // 3*h

typedef __bf16 bf16x8 __attribute__((ext_vector_type(8)));
typedef float  f32x4  __attribute__((ext_vector_type(4)));

#define MFMA16(a, b, c) __builtin_amdgcn_mfma_f32_16x16x32_bf16((a), (b), (c), 0, 0, 0)

// s_waitcnt lgkmcnt(0), vmcnt/expcnt left open (intrinsic form).
#define LGKM_DRAIN() do { \
  __builtin_amdgcn_s_waitcnt(0xC07F); \
  __builtin_amdgcn_wave_barrier(); \
} while (0)

__device__ __forceinline__ uint16_t f2bf_u(float f) {
  union { float f; uint32_t u; } v; v.f = f;
  uint32_t u = v.u;
  u += 0x7fffu + ((u >> 16) & 1u);   // RNE (no NaN inputs here)
  return (uint16_t)(u >> 16);
}

__device__ __forceinline__ bf16x8 ldb8(const uint16_t* p) {
  return *reinterpret_cast<const bf16x8*>(p);
}

// async global->LDS, 16B per lane. LDS dest = wave-uniform base + lane*16.
__device__ __forceinline__ void gll16(const uint16_t* g, uint16_t* l) {
  __builtin_amdgcn_global_load_lds(
      (const __attribute__((address_space(1))) uint32_t*)g,
      (__attribute__((address_space(3))) uint32_t*)l, 16, 0, 0);
}

// ---------------------------------------------------------------------------
// Kernel 1: fp32 -> bf16, 4 elements/thread.
//   xb[t][c] = x[bi][s][c], t = s*2 + bi  (seq-major token order)
// ---------------------------------------------------------------------------
__global__ __launch_bounds__(256) void convert_kernel(
    const float* __restrict__ x, const float* __restrict__ wqkv,
    const float* __restrict__ wproj,
    uint16_t* __restrict__ xb, uint16_t* __restrict__ wqkvb,
    uint16_t* __restrict__ wprojb) {
  const int XT4 = (T_TOK * H) / 4;   // 1048576
  const int WQ4 = (N3H * H) / 4;     // 786432
  int i4 = blockIdx.x * 256 + threadIdx.x;
  const float* src;
  uint16_t* dst;
  if (i4 < XT4) {
    int i = i4 * 4;
    int t = i >> 10, c = i & 1023;
    int bi = t & 1, s = t >> 1;
    src = x + (bi * SQ + s) * H + c;
    dst = xb + i;
  } else if (i4 < XT4 + WQ4) {
    int j = (i4 - XT4) * 4;
    src = wqkv + j; dst = wqkvb + j;
  } else {
    int j = (i4 - XT4 - WQ4) * 4;
    src = wproj + j; dst = wprojb + j;
  }
  float4 v = *(const float4*)src;
  ushort4 o;
  o.x = f2bf_u(v.x); o.y = f2bf_u(v.y); o.z = f2bf_u(v.z); o.w = f2bf_u(v.w);
  *(ushort4*)dst = o;
}

// ---------------------------------------------------------------------------
// Kernel 2: QKV GEMM, m97 structure. C[t][c] = sum_k xb[t][k]*Wqkv[c][k].
// 128x128 block tile, BK=32, global_load_lds width=16 staging, 4 waves in
// 2x2, each wave 64x64 (4x4 MFMA frags).
// ---------------------------------------------------------------------------
__global__ __launch_bounds__(256) void gemm_qkv_kernel(
    const uint16_t* __restrict__ xb, const uint16_t* __restrict__ wb,
    uint16_t* __restrict__ Qb, uint16_t* __restrict__ Kb,
    uint16_t* __restrict__ Vtb) {
  const int lane = threadIdx.x & 63;
  const int wave = threadIdx.x >> 6;
  const int quad = lane >> 4, l16 = lane & 15;
  const int wm = wave >> 1, wn = wave & 1;
  const int row0 = blockIdx.y * 128, col0 = blockIdx.x * 128;

  __shared__ __align__(16) uint16_t sA[128 * 32];
  __shared__ __align__(16) uint16_t sB[128 * 32];

  const int lrow = lane >> 2;        // 0..15
  const int lk   = (lane & 3) * 8;   // k-chunk (8 elems = 16B)

  f32x4 acc[4][4];
#pragma unroll
  for (int i = 0; i < 4; ++i)
#pragma unroll
    for (int j = 0; j < 4; ++j) acc[i][j] = (f32x4){0.f, 0.f, 0.f, 0.f};

  for (int k0 = 0; k0 < H; k0 += 32) {
#pragma unroll
    for (int c = 0; c < 2; ++c) {
      int g = c * 4 + wave;
      gll16(xb + (size_t)(row0 + g * 16 + lrow) * H + k0 + lk, sA + g * 512);
      gll16(wb + (size_t)(col0 + g * 16 + lrow) * H + k0 + lk, sB + g * 512);
    }
    __syncthreads();
    bf16x8 af[4], bfr[4];
#pragma unroll
    for (int mt = 0; mt < 4; ++mt)
      af[mt] = ldb8(sA + (wm * 64 + mt * 16 + l16) * 32 + quad * 8);
#pragma unroll
    for (int nt = 0; nt < 4; ++nt)
      bfr[nt] = ldb8(sB + (wn * 64 + nt * 16 + l16) * 32 + quad * 8);
#pragma unroll
    for (int mt = 0; mt < 4; ++mt)
#pragma unroll
      for (int nt = 0; nt < 4; ++nt)
        acc[mt][nt] = MFMA16(af[mt], bfr[nt], acc[mt][nt]);
    __syncthreads();
  }

#pragma unroll
  for (int mt = 0; mt < 4; ++mt)
#pragma unroll
    for (int nt = 0; nt < 4; ++nt)
#pragma unroll
      for (int r = 0; r < 4; ++r) {
        int m = row0 + wm * 64 + mt * 16 + quad * 4 + r;  // token t
        int c = col0 + wn * 64 + nt * 16 + l16;           // qkv column
        int hd = c / 192;
        int rr = c - hd * 192;
        int which = rr >> 6;
        int d = rr & 63;
        int s = m >> 1, bi = m & 1;
        int n = bi * NH + hd;
        uint16_t bv = f2bf_u(acc[mt][nt][r]);
        if (which == 0)      Qb[(n * SQ + s) * HN + d] = bv;
        else if (which == 1) Kb[(n * SQ + s) * HN + d] = bv;
        else                 Vtb[(n * HN + d) * SQ + s] = bv;
      }
}

// ---------------------------------------------------------------------------
// Kernel 3: flash attention, k-split x2 for occupancy.
// 512-thread blocks (8 waves): waves 0-3 = q-subtiles 0-3 over kt 0..15,
// waves 4-7 = same q-subtiles over kt 16..31. No max-tracking => partials
// combine LINEARLY (acc + acc, lsum + lsum) via LDS + one __syncthreads.
// 8192 waves total = 8 waves/SIMD at VGPR<=64 (vs 4 before — the r2/r4
// structure was grid-capped at 4 waves/SIMD with fully-exposed L2 latency).
// Per-wave dataflow identical to the proven r2 formulation.
// ---------------------------------------------------------------------------
__global__ __launch_bounds__(512, 8) void attn_kernel(
    const uint16_t* __restrict__ Qb, const uint16_t* __restrict__ Kb,
    const uint16_t* __restrict__ Vtb, uint16_t* __restrict__ ctxb) {
  const int lane = threadIdx.x & 63;
  const int wave = threadIdx.x >> 6;        // 0..7
  const int quad = lane >> 4, l16 = lane & 15;
  const int head  = blockIdx.x;   // n = bi*16 + hd
  const int qtile = blockIdx.y;
  const int wq = wave & 3;                  // q-subtile
  const int half = wave >> 2;               // k-range half
  const int q0 = qtile * 64 + wq * 16;
  const int kt0 = half * 16;                // 16 kt-tiles per wave

  const uint16_t* Qh = Qb + (size_t)head * SQ * HN;
  const uint16_t* Kh = Kb + (size_t)head * SQ * HN;
  const uint16_t* Vh = Vtb + (size_t)head * HN * SQ;

  __shared__ __align__(16) uint16_t plds[8][16][72];   // per-wave P tile
  __shared__ float cacc[4][64][21];                    // combine buffer (padded)

  // Q fragments, persistent (two K=32 chunks over d)
  bf16x8 aq0 = ldb8(Qh + (q0 + l16) * HN + quad * 8);
  bf16x8 aq1 = ldb8(Qh + (q0 + l16) * HN + 32 + quad * 8);

  float lrun[4];
  f32x4 acc[4];
#pragma unroll
  for (int r = 0; r < 4; ++r) {
    lrun[r] = 0.f;
    acc[r] = (f32x4){0.f, 0.f, 0.f, 0.f};
  }
  const float sc2 = 0.125f * 1.44269504f;   // 1/sqrt(64) * log2(e)

  // preload K fragments for first tile of this wave's range
  bf16x8 kf[4][2];
#pragma unroll
  for (int st = 0; st < 4; ++st) {
    kf[st][0] = ldb8(Kh + (kt0 * 64 + st * 16 + l16) * HN + quad * 8);
    kf[st][1] = ldb8(Kh + (kt0 * 64 + st * 16 + l16) * HN + 32 + quad * 8);
  }

  for (int kt = kt0; kt < kt0 + 16; ++kt) {
    const int kbase = kt * 64;
    // V fragments for this tile (issued early to overlap softmax)
    bf16x8 vf[4][2];
#pragma unroll
    for (int dt = 0; dt < 4; ++dt) {
      vf[dt][0] = ldb8(Vh + (dt * 16 + l16) * SQ + kbase + quad * 8);
      vf[dt][1] = ldb8(Vh + (dt * 16 + l16) * SQ + kbase + 32 + quad * 8);
    }
    // --- S = Q K^T ---
    f32x4 s4[4];
#pragma unroll
    for (int st = 0; st < 4; ++st) {
      f32x4 z = (f32x4){0.f, 0.f, 0.f, 0.f};
      z = MFMA16(aq0, kf[st][0], z);
      s4[st] = MFMA16(aq1, kf[st][1], z);
    }
    // --- prefetch next K tile ---
    if (kt < kt0 + 15) {
      const int kb2 = kbase + 64;
#pragma unroll
      for (int st = 0; st < 4; ++st) {
        kf[st][0] = ldb8(Kh + (kb2 + st * 16 + l16) * HN + quad * 8);
        kf[st][1] = ldb8(Kh + (kb2 + st * 16 + l16) * HN + 32 + quad * 8);
      }
    }
    // --- exp2-domain softmax, no max-tracking, per-lane partial sums ---
#pragma unroll
    for (int st = 0; st < 4; ++st)
#pragma unroll
      for (int r = 0; r < 4; ++r) {
        float p = __builtin_amdgcn_exp2f(s4[st][r] * sc2);
        plds[wave][quad * 4 + r][st * 16 + l16] = f2bf_u(p);
        lrun[r] += p;
      }
    // drain this wave's LDS writes only (same-wave DS ops are in-order)
    LGKM_DRAIN();
    bf16x8 ap0 = ldb8(&plds[wave][l16][quad * 8]);
    bf16x8 ap1 = ldb8(&plds[wave][l16][32 + quad * 8]);
    // --- ctx += P @ V ---
#pragma unroll
    for (int dt = 0; dt < 4; ++dt) {
      acc[dt] = MFMA16(ap0, vf[dt][0], acc[dt]);
      acc[dt] = MFMA16(ap1, vf[dt][1], acc[dt]);
    }
  }

  // --- k-split combine: upper-half waves publish partials, lower halves add ---
  if (half) {
    float* dst = cacc[wq][lane];
#pragma unroll
    for (int dt = 0; dt < 4; ++dt)
#pragma unroll
      for (int r = 0; r < 4; ++r) dst[dt * 4 + r] = acc[dt][r];
#pragma unroll
    for (int r = 0; r < 4; ++r) dst[16 + r] = lrun[r];
  }
  __syncthreads();
  if (half) return;
  {
    const float* src = cacc[wq][lane];
#pragma unroll
    for (int dt = 0; dt < 4; ++dt)
#pragma unroll
      for (int r = 0; r < 4; ++r) acc[dt][r] += src[dt * 4 + r];
#pragma unroll
    for (int r = 0; r < 4; ++r) lrun[r] += src[16 + r];
  }

  // --- epilogue: one 16-lane reduction of the row sums, then normalize ---
  float rinv[4];
#pragma unroll
  for (int r = 0; r < 4; ++r) {
    float ls = lrun[r];
    ls += __shfl_xor(ls, 1);
    ls += __shfl_xor(ls, 2);
    ls += __shfl_xor(ls, 4);
    ls += __shfl_xor(ls, 8);
    rinv[r] = __builtin_amdgcn_rcpf(ls);
  }
#pragma unroll
  for (int dt = 0; dt < 4; ++dt)
#pragma unroll
    for (int r = 0; r < 4; ++r) {
      int qg = q0 + quad * 4 + r;
      int dg = dt * 16 + l16;
      float v = acc[dt][r] * rinv[r];
      int row = qg * 2 + (head & 1);             // reference (nh,b) view scramble
      int col = (head >> 1) * HN + dg;
      ctxb[row * H + col] = f2bf_u(v);
    }
}

// ---------------------------------------------------------------------------
// Kernel 4: projection + bias, m97 structure, 128(M)x64(N) tile
// (512 blocks -> 2/CU). Waves stacked in M (32 rows each, 2x4 frags).
// ---------------------------------------------------------------------------
__global__ __launch_bounds__(256) void gemm_proj_kernel(
    const uint16_t* __restrict__ ab, const uint16_t* __restrict__ wb,
    const float* __restrict__ bias, float* __restrict__ out) {
  const int lane = threadIdx.x & 63;
  const int wave = threadIdx.x >> 6;
  const int quad = lane >> 4, l16 = lane & 15;
  const int row0 = blockIdx.y * 128, col0 = blockIdx.x * 64;

  __shared__ __align__(16) uint16_t sA[128 * 32];
  __shared__ __align__(16) uint16_t sB[64 * 32];

  const int lrow = lane >> 2;
  const int lk   = (lane & 3) * 8;

  f32x4 acc[2][4];
#pragma unroll
  for (int i = 0; i < 2; ++i)
#pragma unroll
    for (int j = 0; j < 4; ++j) acc[i][j] = (f32x4){0.f, 0.f, 0.f, 0.f};

  for (int k0 = 0; k0 < H; k0 += 32) {
#pragma unroll
    for (int c = 0; c < 2; ++c) {
      int g = c * 4 + wave;
      gll16(ab + (size_t)(row0 + g * 16 + lrow) * H + k0 + lk, sA + g * 512);
    }
    gll16(wb + (size_t)(col0 + wave * 16 + lrow) * H + k0 + lk, sB + wave * 512);
    __syncthreads();
    bf16x8 af[2], bfr[4];
#pragma unroll
    for (int mt = 0; mt < 2; ++mt)
      af[mt] = ldb8(sA + (wave * 32 + mt * 16 + l16) * 32 + quad * 8);
#pragma unroll
    for (int nt = 0; nt < 4; ++nt)
      bfr[nt] = ldb8(sB + (nt * 16 + l16) * 32 + quad * 8);
#pragma unroll
    for (int mt = 0; mt < 2; ++mt)
#pragma unroll
      for (int nt = 0; nt < 4; ++nt)
        acc[mt][nt] = MFMA16(af[mt], bfr[nt], acc[mt][nt]);
    __syncthreads();
  }

#pragma unroll
  for (int mt = 0; mt < 2; ++mt)
#pragma unroll
    for (int nt = 0; nt < 4; ++nt)
#pragma unroll
      for (int r = 0; r < 4; ++r) {
        int m = row0 + wave * 32 + mt * 16 + quad * 4 + r;  // t' = s*2+bi
        int c = col0 + nt * 16 + l16;
        int s = m >> 1, bi = m & 1;
        out[(size_t)(bi * SQ + s) * H + c] = acc[mt][nt][r] + bias[c];
      }
}

// ---------------------------------------------------------------------------
extern "C" void kernel_launch(void* const* d_in, const int* in_sizes, int n_in,
                              void* d_out, int out_size, void* d_ws, size_t ws_size,
                              hipStream_t stream) {
  const float* x     = (const float*)d_in[0];
  const float* wqkv  = (const float*)d_in[3];
  const float* wproj = (const float*)d_in[4];
  const float* bproj = (const float*)d_in[5];
  float* out = (float*)d_out;

  char* ws = (char*)d_ws;
  uint16_t* xb     = (uint16_t*)(ws);                        //  8 MB
  uint16_t* wqkvb  = (uint16_t*)(ws + (8ull  << 20));        //  6 MB
  uint16_t* wprojb = (uint16_t*)(ws + (14ull << 20));        //  2 MB
  uint16_t* Qb     = (uint16_t*)(ws + (16ull << 20));        //  8 MB [32][2048][64]
  uint16_t* Kb     = (uint16_t*)(ws + (24ull << 20));        //  8 MB [32][2048][64]
  uint16_t* Vtb    = (uint16_t*)(ws + (32ull << 20));        //  8 MB [32][64][2048]
  uint16_t* ctxb   = (uint16_t*)(ws + (40ull << 20));        //  8 MB [4096][1024]

  convert_kernel<<<8192, 256, 0, stream>>>(x, wqkv, wproj, xb, wqkvb, wprojb);
  gemm_qkv_kernel<<<dim3(N3H / 128, T_TOK / 128), 256, 0, stream>>>(xb, wqkvb, Qb, Kb, Vtb);
  attn_kernel<<<dim3(B_ * NH, SQ / 64), 512, 0, stream>>>(Qb, Kb, Vtb, ctxb);
  gemm_proj_kernel<<<dim3(H / 64, T_TOK / 128), 256, 0, stream>>>(ctxb, wprojb, bproj, out);
}

// Round 6
// 236.918 us; speedup vs baseline: 3.6249x; 3.6249x over previous
//
#include <hip/hip_runtime.h>
#include <stdint.h>

// Problem constants
#define B_   2
#define SQ   2048
#define H    1024
#define NH   16
#define HN   64
#define T_TOK 4096          // sq*b tokens
#define N3H  3072           // 3*h

typedef __bf16 bf16x8 __attribute__((ext_vector_type(8)));
typedef float  f32x4  __attribute__((ext_vector_type(4)));

#define MFMA16(a, b, c) __builtin_amdgcn_mfma_f32_16x16x32_bf16((a), (b), (c), 0, 0, 0)

// s_waitcnt lgkmcnt(0), vmcnt/expcnt left open (intrinsic form).
#define LGKM_DRAIN() do { \
  __builtin_amdgcn_s_waitcnt(0xC07F); \
  __builtin_amdgcn_wave_barrier(); \
} while (0)

__device__ __forceinline__ uint16_t f2bf_u(float f) {
  union { float f; uint32_t u; } v; v.f = f;
  uint32_t u = v.u;
  u += 0x7fffu + ((u >> 16) & 1u);   // RNE (no NaN inputs here)
  return (uint16_t)(u >> 16);
}

__device__ __forceinline__ bf16x8 ldb8(const uint16_t* p) {
  return *reinterpret_cast<const bf16x8*>(p);
}

// async global->LDS, 16B per lane. LDS dest = wave-uniform base + lane*16.
__device__ __forceinline__ void gll16(const uint16_t* g, uint16_t* l) {
  __builtin_amdgcn_global_load_lds(
      (const __attribute__((address_space(1))) uint32_t*)g,
      (__attribute__((address_space(3))) uint32_t*)l, 16, 0, 0);
}

// ---------------------------------------------------------------------------
// Kernel 1: fp32 -> bf16, 4 elements/thread.
// ---------------------------------------------------------------------------
__global__ __launch_bounds__(256) void convert_kernel(
    const float* __restrict__ x, const float* __restrict__ wqkv,
    const float* __restrict__ wproj,
    uint16_t* __restrict__ xb, uint16_t* __restrict__ wqkvb,
    uint16_t* __restrict__ wprojb) {
  const int XT4 = (T_TOK * H) / 4;   // 1048576
  const int WQ4 = (N3H * H) / 4;     // 786432
  int i4 = blockIdx.x * 256 + threadIdx.x;
  const float* src;
  uint16_t* dst;
  if (i4 < XT4) {
    int i = i4 * 4;
    int t = i >> 10, c = i & 1023;
    int bi = t & 1, s = t >> 1;
    src = x + (bi * SQ + s) * H + c;
    dst = xb + i;
  } else if (i4 < XT4 + WQ4) {
    int j = (i4 - XT4) * 4;
    src = wqkv + j; dst = wqkvb + j;
  } else {
    int j = (i4 - XT4 - WQ4) * 4;
    src = wproj + j; dst = wprojb + j;
  }
  float4 v = *(const float4*)src;
  ushort4 o;
  o.x = f2bf_u(v.x); o.y = f2bf_u(v.y); o.z = f2bf_u(v.z); o.w = f2bf_u(v.w);
  *(ushort4*)dst = o;
}

// ---------------------------------------------------------------------------
// Kernel 2: QKV GEMM, m97 structure (unchanged from r4).
// ---------------------------------------------------------------------------
__global__ __launch_bounds__(256) void gemm_qkv_kernel(
    const uint16_t* __restrict__ xb, const uint16_t* __restrict__ wb,
    uint16_t* __restrict__ Qb, uint16_t* __restrict__ Kb,
    uint16_t* __restrict__ Vtb) {
  const int lane = threadIdx.x & 63;
  const int wave = threadIdx.x >> 6;
  const int quad = lane >> 4, l16 = lane & 15;
  const int wm = wave >> 1, wn = wave & 1;
  const int row0 = blockIdx.y * 128, col0 = blockIdx.x * 128;

  __shared__ __align__(16) uint16_t sA[128 * 32];
  __shared__ __align__(16) uint16_t sB[128 * 32];

  const int lrow = lane >> 2;        // 0..15
  const int lk   = (lane & 3) * 8;   // k-chunk (8 elems = 16B)

  f32x4 acc[4][4];
#pragma unroll
  for (int i = 0; i < 4; ++i)
#pragma unroll
    for (int j = 0; j < 4; ++j) acc[i][j] = (f32x4){0.f, 0.f, 0.f, 0.f};

  for (int k0 = 0; k0 < H; k0 += 32) {
#pragma unroll
    for (int c = 0; c < 2; ++c) {
      int g = c * 4 + wave;
      gll16(xb + (size_t)(row0 + g * 16 + lrow) * H + k0 + lk, sA + g * 512);
      gll16(wb + (size_t)(col0 + g * 16 + lrow) * H + k0 + lk, sB + g * 512);
    }
    __syncthreads();
    bf16x8 af[4], bfr[4];
#pragma unroll
    for (int mt = 0; mt < 4; ++mt)
      af[mt] = ldb8(sA + (wm * 64 + mt * 16 + l16) * 32 + quad * 8);
#pragma unroll
    for (int nt = 0; nt < 4; ++nt)
      bfr[nt] = ldb8(sB + (wn * 64 + nt * 16 + l16) * 32 + quad * 8);
#pragma unroll
    for (int mt = 0; mt < 4; ++mt)
#pragma unroll
      for (int nt = 0; nt < 4; ++nt)
        acc[mt][nt] = MFMA16(af[mt], bfr[nt], acc[mt][nt]);
    __syncthreads();
  }

#pragma unroll
  for (int mt = 0; mt < 4; ++mt)
#pragma unroll
    for (int nt = 0; nt < 4; ++nt)
#pragma unroll
      for (int r = 0; r < 4; ++r) {
        int m = row0 + wm * 64 + mt * 16 + quad * 4 + r;  // token t
        int c = col0 + wn * 64 + nt * 16 + l16;           // qkv column
        int hd = c / 192;
        int rr = c - hd * 192;
        int which = rr >> 6;
        int d = rr & 63;
        int s = m >> 1, bi = m & 1;
        int n = bi * NH + hd;
        uint16_t bv = f2bf_u(acc[mt][nt][r]);
        if (which == 0)      Qb[(n * SQ + s) * HN + d] = bv;
        else if (which == 1) Kb[(n * SQ + s) * HN + d] = bv;
        else                 Vtb[(n * HN + d) * SQ + s] = bv;
      }
}

// ---------------------------------------------------------------------------
// Kernel 3: flash attention, k-split x2 in-block + LDS K/V staging.
// 512 threads = 8 waves: waves 0-3 = q-subtiles 0-3 over kt 0..15,
// waves 4-7 = same over kt 16..31. Each 4-wave group shares its K/V tile,
// staged to LDS via global_load_lds (ZERO VGPR cost — r5's reg-prefetch
// design spilled at 8 waves/SIMD). Staging layout is row-rotated
// (phys chunk = (c8 + row) & 7) so contiguous-lane staging coexists with
// conflict-free ds_read_b128 frag reads. m97-style 2 barriers/iter.
// LDS 50 KB -> 3 blocks/CU = 6 waves/SIMD at VGPR<=84 (no spill).
// Partials combine linearly in LDS (no max-tracking), combine buffer
// aliases the dead staging region.
// ---------------------------------------------------------------------------
__global__ __launch_bounds__(512, 6) void attn_kernel(
    const uint16_t* __restrict__ Qb, const uint16_t* __restrict__ Kb,
    const uint16_t* __restrict__ Vtb, uint16_t* __restrict__ ctxb) {
  const int lane = threadIdx.x & 63;
  const int wave = threadIdx.x >> 6;        // 0..7
  const int quad = lane >> 4, l16 = lane & 15;
  const int head  = blockIdx.x;   // n = bi*16 + hd
  const int qtile = blockIdx.y;
  const int wq = wave & 3;                  // q-subtile
  const int hf = wave >> 2;                 // k-range half
  const int q0 = qtile * 64 + wq * 16;

  const uint16_t* Qh = Qb + (size_t)head * SQ * HN;
  const uint16_t* Kh = Kb + (size_t)head * SQ * HN;
  const uint16_t* Vh = Vtb + (size_t)head * HN * SQ;

  // LDS: [0,32768) staging stage[hf][kv][64][64]  (aliased by combine buf)
  //      [32768,51200) P tiles plds[8][16][72]
  __shared__ __align__(16) char smem_raw[51200];
  uint16_t (*stage)[2][64][64] = (uint16_t(*)[2][64][64])smem_raw;
  float (*cacc)[64][21]        = (float(*)[64][21])smem_raw;
  uint16_t (*plds)[16][72]     = (uint16_t(*)[16][72])(smem_raw + 32768);

  const int lr8 = lane >> 3;            // row-within-8
  const int lc8 = lane & 7;             // phys 16B chunk
  const int sc8 = (lc8 - lr8) & 7;      // logical chunk this lane fetches

  // Q fragments, persistent
  bf16x8 aq0 = ldb8(Qh + (q0 + l16) * HN + quad * 8);
  bf16x8 aq1 = ldb8(Qh + (q0 + l16) * HN + 32 + quad * 8);

  float lrun[4];
  f32x4 acc[4];
#pragma unroll
  for (int r = 0; r < 4; ++r) {
    lrun[r] = 0.f;
    acc[r] = (f32x4){0.f, 0.f, 0.f, 0.f};
  }
  const float sc2 = 0.125f * 1.44269504f;   // 1/sqrt(64) * log2(e)

  for (int kt = 0; kt < 16; ++kt) {
    const int kbase = (hf * 16 + kt) * 64;
    // --- stage K tile rows + V^T tile rows for this half (4 gll16/wave) ---
#pragma unroll
    for (int j = 0; j < 2; ++j) {
      int rr = wq * 16 + j * 8;
      gll16(Kh + (size_t)(kbase + rr + lr8) * HN + sc8 * 8, &stage[hf][0][rr][0]);
      gll16(Vh + (size_t)(rr + lr8) * SQ + kbase + sc8 * 8, &stage[hf][1][rr][0]);
    }
    __syncthreads();   // staging complete (auto vmcnt(0) before barrier)

    // --- S = Q K^T (frags straight from swizzled LDS) ---
    f32x4 s4[4];
#pragma unroll
    for (int st = 0; st < 4; ++st) {
      bf16x8 k0 = ldb8(&stage[hf][0][st * 16 + l16][0] + ((quad + l16) & 7) * 8);
      bf16x8 k1 = ldb8(&stage[hf][0][st * 16 + l16][0] + ((quad + 4 + l16) & 7) * 8);
      f32x4 z = (f32x4){0.f, 0.f, 0.f, 0.f};
      z = MFMA16(aq0, k0, z);
      s4[st] = MFMA16(aq1, k1, z);
    }
    // --- exp2-domain softmax, P -> per-wave LDS, per-lane partial sums ---
#pragma unroll
    for (int st = 0; st < 4; ++st)
#pragma unroll
      for (int r = 0; r < 4; ++r) {
        float p = __builtin_amdgcn_exp2f(s4[st][r] * sc2);
        plds[wave][quad * 4 + r][st * 16 + l16] = f2bf_u(p);
        lrun[r] += p;
      }
    LGKM_DRAIN();      // same-wave DS ordering only
    bf16x8 ap0 = ldb8(&plds[wave][l16][quad * 8]);
    bf16x8 ap1 = ldb8(&plds[wave][l16][32 + quad * 8]);
    // --- ctx += P @ V ---
#pragma unroll
    for (int dt = 0; dt < 4; ++dt) {
      bf16x8 v0 = ldb8(&stage[hf][1][dt * 16 + l16][0] + ((quad + l16) & 7) * 8);
      bf16x8 v1 = ldb8(&stage[hf][1][dt * 16 + l16][0] + ((quad + 4 + l16) & 7) * 8);
      acc[dt] = MFMA16(ap0, v0, acc[dt]);
      acc[dt] = MFMA16(ap1, v1, acc[dt]);
    }
    __syncthreads();   // all frag reads done before next staging
  }

  // --- k-split combine (linear: no max-tracking) via aliased LDS ---
  if (hf) {
    float* dst = cacc[wq][lane];
#pragma unroll
    for (int dt = 0; dt < 4; ++dt)
#pragma unroll
      for (int r = 0; r < 4; ++r) dst[dt * 4 + r] = acc[dt][r];
#pragma unroll
    for (int r = 0; r < 4; ++r) dst[16 + r] = lrun[r];
  }
  __syncthreads();
  if (hf) return;
  {
    const float* src = cacc[wq][lane];
#pragma unroll
    for (int dt = 0; dt < 4; ++dt)
#pragma unroll
      for (int r = 0; r < 4; ++r) acc[dt][r] += src[dt * 4 + r];
#pragma unroll
    for (int r = 0; r < 4; ++r) lrun[r] += src[16 + r];
  }

  // --- epilogue: 16-lane row-sum reduction, normalize, scrambled store ---
  float rinv[4];
#pragma unroll
  for (int r = 0; r < 4; ++r) {
    float ls = lrun[r];
    ls += __shfl_xor(ls, 1);
    ls += __shfl_xor(ls, 2);
    ls += __shfl_xor(ls, 4);
    ls += __shfl_xor(ls, 8);
    rinv[r] = __builtin_amdgcn_rcpf(ls);
  }
#pragma unroll
  for (int dt = 0; dt < 4; ++dt)
#pragma unroll
    for (int r = 0; r < 4; ++r) {
      int qg = q0 + quad * 4 + r;
      int dg = dt * 16 + l16;
      float v = acc[dt][r] * rinv[r];
      int row = qg * 2 + (head & 1);             // reference (nh,b) view scramble
      int col = (head >> 1) * HN + dg;
      ctxb[row * H + col] = f2bf_u(v);
    }
}

// ---------------------------------------------------------------------------
// Kernel 4: projection + bias, m97 structure (unchanged from r4).
// ---------------------------------------------------------------------------
__global__ __launch_bounds__(256) void gemm_proj_kernel(
    const uint16_t* __restrict__ ab, const uint16_t* __restrict__ wb,
    const float* __restrict__ bias, float* __restrict__ out) {
  const int lane = threadIdx.x & 63;
  const int wave = threadIdx.x >> 6;
  const int quad = lane >> 4, l16 = lane & 15;
  const int row0 = blockIdx.y * 128, col0 = blockIdx.x * 64;

  __shared__ __align__(16) uint16_t sA[128 * 32];
  __shared__ __align__(16) uint16_t sB[64 * 32];

  const int lrow = lane >> 2;
  const int lk   = (lane & 3) * 8;

  f32x4 acc[2][4];
#pragma unroll
  for (int i = 0; i < 2; ++i)
#pragma unroll
    for (int j = 0; j < 4; ++j) acc[i][j] = (f32x4){0.f, 0.f, 0.f, 0.f};

  for (int k0 = 0; k0 < H; k0 += 32) {
#pragma unroll
    for (int c = 0; c < 2; ++c) {
      int g = c * 4 + wave;
      gll16(ab + (size_t)(row0 + g * 16 + lrow) * H + k0 + lk, sA + g * 512);
    }
    gll16(wb + (size_t)(col0 + wave * 16 + lrow) * H + k0 + lk, sB + wave * 512);
    __syncthreads();
    bf16x8 af[2], bfr[4];
#pragma unroll
    for (int mt = 0; mt < 2; ++mt)
      af[mt] = ldb8(sA + (wave * 32 + mt * 16 + l16) * 32 + quad * 8);
#pragma unroll
    for (int nt = 0; nt < 4; ++nt)
      bfr[nt] = ldb8(sB + (nt * 16 + l16) * 32 + quad * 8);
#pragma unroll
    for (int mt = 0; mt < 2; ++mt)
#pragma unroll
      for (int nt = 0; nt < 4; ++nt)
        acc[mt][nt] = MFMA16(af[mt], bfr[nt], acc[mt][nt]);
    __syncthreads();
  }

#pragma unroll
  for (int mt = 0; mt < 2; ++mt)
#pragma unroll
    for (int nt = 0; nt < 4; ++nt)
#pragma unroll
      for (int r = 0; r < 4; ++r) {
        int m = row0 + wave * 32 + mt * 16 + quad * 4 + r;  // t' = s*2+bi
        int c = col0 + nt * 16 + l16;
        int s = m >> 1, bi = m & 1;
        out[(size_t)(bi * SQ + s) * H + c] = acc[mt][nt][r] + bias[c];
      }
}

// ---------------------------------------------------------------------------
extern "C" void kernel_launch(void* const* d_in, const int* in_sizes, int n_in,
                              void* d_out, int out_size, void* d_ws, size_t ws_size,
                              hipStream_t stream) {
  const float* x     = (const float*)d_in[0];
  const float* wqkv  = (const float*)d_in[3];
  const float* wproj = (const float*)d_in[4];
  const float* bproj = (const float*)d_in[5];
  float* out = (float*)d_out;

  char* ws = (char*)d_ws;
  uint16_t* xb     = (uint16_t*)(ws);                        //  8 MB
  uint16_t* wqkvb  = (uint16_t*)(ws + (8ull  << 20));        //  6 MB
  uint16_t* wprojb = (uint16_t*)(ws + (14ull << 20));        //  2 MB
  uint16_t* Qb     = (uint16_t*)(ws + (16ull << 20));        //  8 MB [32][2048][64]
  uint16_t* Kb     = (uint16_t*)(ws + (24ull << 20));        //  8 MB [32][2048][64]
  uint16_t* Vtb    = (uint16_t*)(ws + (32ull << 20));        //  8 MB [32][64][2048]
  uint16_t* ctxb   = (uint16_t*)(ws + (40ull << 20));        //  8 MB [4096][1024]

  convert_kernel<<<8192, 256, 0, stream>>>(x, wqkv, wproj, xb, wqkvb, wprojb);
  gemm_qkv_kernel<<<dim3(N3H / 128, T_TOK / 128), 256, 0, stream>>>(xb, wqkvb, Qb, Kb, Vtb);
  attn_kernel<<<dim3(B_ * NH, SQ / 64), 512, 0, stream>>>(Qb, Kb, Vtb, ctxb);
  gemm_proj_kernel<<<dim3(H / 64, T_TOK / 128), 256, 0, stream>>>(ctxb, wprojb, bproj, out);
}

// Round 7
// 227.394 us; speedup vs baseline: 3.7767x; 1.0419x over previous
//
#include <hip/hip_runtime.h>
#include <stdint.h>

// Problem constants
#define B_   2
#define SQ   2048
#define H    1024
#define NH   16
#define HN   64
#define T_TOK 4096          // sq*b tokens
#define N3H  3072           // 3*h

typedef __bf16 bf16x8 __attribute__((ext_vector_type(8)));
typedef float  f32x4  __attribute__((ext_vector_type(4)));

#define MFMA16(a, b, c) __builtin_amdgcn_mfma_f32_16x16x32_bf16((a), (b), (c), 0, 0, 0)

// s_waitcnt lgkmcnt(0), vmcnt/expcnt left open (intrinsic form).
#define LGKM_DRAIN() do { \
  __builtin_amdgcn_s_waitcnt(0xC07F); \
  __builtin_amdgcn_wave_barrier(); \
} while (0)

__device__ __forceinline__ uint16_t f2bf_u(float f) {
  union { float f; uint32_t u; } v; v.f = f;
  uint32_t u = v.u;
  u += 0x7fffu + ((u >> 16) & 1u);   // RNE (no NaN inputs here)
  return (uint16_t)(u >> 16);
}

__device__ __forceinline__ bf16x8 ldb8(const uint16_t* p) {
  return *reinterpret_cast<const bf16x8*>(p);
}

// async global->LDS, 16B per lane. LDS dest = wave-uniform base + lane*16.
__device__ __forceinline__ void gll16(const uint16_t* g, uint16_t* l) {
  __builtin_amdgcn_global_load_lds(
      (const __attribute__((address_space(1))) uint32_t*)g,
      (__attribute__((address_space(3))) uint32_t*)l, 16, 0, 0);
}

// ---------------------------------------------------------------------------
// Kernel 1: fp32 -> bf16, 4 elements/thread.
// ---------------------------------------------------------------------------
__global__ __launch_bounds__(256) void convert_kernel(
    const float* __restrict__ x, const float* __restrict__ wqkv,
    const float* __restrict__ wproj,
    uint16_t* __restrict__ xb, uint16_t* __restrict__ wqkvb,
    uint16_t* __restrict__ wprojb) {
  const int XT4 = (T_TOK * H) / 4;   // 1048576
  const int WQ4 = (N3H * H) / 4;     // 786432
  int i4 = blockIdx.x * 256 + threadIdx.x;
  const float* src;
  uint16_t* dst;
  if (i4 < XT4) {
    int i = i4 * 4;
    int t = i >> 10, c = i & 1023;
    int bi = t & 1, s = t >> 1;
    src = x + (bi * SQ + s) * H + c;
    dst = xb + i;
  } else if (i4 < XT4 + WQ4) {
    int j = (i4 - XT4) * 4;
    src = wqkv + j; dst = wqkvb + j;
  } else {
    int j = (i4 - XT4 - WQ4) * 4;
    src = wproj + j; dst = wprojb + j;
  }
  float4 v = *(const float4*)src;
  ushort4 o;
  o.x = f2bf_u(v.x); o.y = f2bf_u(v.y); o.z = f2bf_u(v.z); o.w = f2bf_u(v.w);
  *(ushort4*)dst = o;
}

// ---------------------------------------------------------------------------
// Kernel 2: QKV GEMM, m97 structure. NEW epilogue: each wave's 64-col strip
// maps WHOLLY to Q, K, or V of one head (col tiles are 64-aligned), so
// which/hd are wave-uniform. Round-trip the 64x64 wave tile through private
// LDS (stride 76 de-phases quads) and store 16B/lane coalesced:
//   Q/K: [t][d] rows -> 128B-contiguous runs
//   V  : transposed to [d][bi][s] -> 64B-contiguous runs (was 2B scatter!)
// ---------------------------------------------------------------------------
__global__ __launch_bounds__(256) void gemm_qkv_kernel(
    const uint16_t* __restrict__ xb, const uint16_t* __restrict__ wb,
    uint16_t* __restrict__ Qb, uint16_t* __restrict__ Kb,
    uint16_t* __restrict__ Vtb) {
  const int lane = threadIdx.x & 63;
  const int wave = threadIdx.x >> 6;
  const int quad = lane >> 4, l16 = lane & 15;
  const int wm = wave >> 1, wn = wave & 1;
  const int row0 = blockIdx.y * 128, col0 = blockIdx.x * 128;

  // union: staging (16 KB) and epilogue scratch (4 x 9728 B = 38912 B)
  __shared__ __align__(16) char smem[4 * 64 * 76 * 2];
  uint16_t* sA = (uint16_t*)smem;            // 128*32
  uint16_t* sB = (uint16_t*)(smem + 8192);   // 128*32
  uint16_t* W  = (uint16_t*)(smem) + wave * (64 * 76);

  const int lrow = lane >> 2;        // 0..15
  const int lk   = (lane & 3) * 8;   // k-chunk (8 elems = 16B)

  f32x4 acc[4][4];
#pragma unroll
  for (int i = 0; i < 4; ++i)
#pragma unroll
    for (int j = 0; j < 4; ++j) acc[i][j] = (f32x4){0.f, 0.f, 0.f, 0.f};

  for (int k0 = 0; k0 < H; k0 += 32) {
#pragma unroll
    for (int c = 0; c < 2; ++c) {
      int g = c * 4 + wave;
      gll16(xb + (size_t)(row0 + g * 16 + lrow) * H + k0 + lk, sA + g * 512);
      gll16(wb + (size_t)(col0 + g * 16 + lrow) * H + k0 + lk, sB + g * 512);
    }
    __syncthreads();
    bf16x8 af[4], bfr[4];
#pragma unroll
    for (int mt = 0; mt < 4; ++mt)
      af[mt] = ldb8(sA + (wm * 64 + mt * 16 + l16) * 32 + quad * 8);
#pragma unroll
    for (int nt = 0; nt < 4; ++nt)
      bfr[nt] = ldb8(sB + (wn * 64 + nt * 16 + l16) * 32 + quad * 8);
#pragma unroll
    for (int mt = 0; mt < 4; ++mt)
#pragma unroll
      for (int nt = 0; nt < 4; ++nt)
        acc[mt][nt] = MFMA16(af[mt], bfr[nt], acc[mt][nt]);
    __syncthreads();   // also protects smem reuse by the epilogue below
  }

  // ---- epilogue (wave-uniform routing; no divs, no branches per element) ---
  const int c0 = col0 + wn * 64;       // 64-aligned
  const int cm = c0 >> 6;              // 0..47
  const int hd = cm / 3;               // head (compile-time magic-mul)
  const int which = cm - hd * 3;       // 0=Q 1=K 2=V
  const int t0 = row0 + wm * 64;

  if (which < 2) {
    // LDS tile [t_local][d], stride 76
#pragma unroll
    for (int mt = 0; mt < 4; ++mt)
#pragma unroll
      for (int nt = 0; nt < 4; ++nt)
#pragma unroll
        for (int r = 0; r < 4; ++r)
          W[(mt * 16 + quad * 4 + r) * 76 + nt * 16 + l16] = f2bf_u(acc[mt][nt][r]);
    LGKM_DRAIN();
    uint16_t* dstb = (which == 0) ? Qb : Kb;
    const int t8 = lane >> 3, d0 = (lane & 7) * 8;
#pragma unroll
    for (int it = 0; it < 8; ++it) {
      int tl = it * 8 + t8;
      int t = t0 + tl;
      int s = t >> 1;
      int n = (t & 1) * NH + hd;
      bf16x8 vv = ldb8(W + tl * 76 + d0);
      *(bf16x8*)(dstb + (size_t)(n * SQ + s) * HN + d0) = vv;
    }
  } else {
    // V: LDS tile [d][bi*32 + s_local], stride 76; packed u32 writes
    uint32_t* W32 = (uint32_t*)W;
#pragma unroll
    for (int mt = 0; mt < 4; ++mt)
#pragma unroll
      for (int nt = 0; nt < 4; ++nt) {
        int base = (nt * 16 + l16) * 76 + mt * 8 + quad * 2;   // even
        W32[base >> 1] =
            (uint32_t)f2bf_u(acc[mt][nt][0]) | ((uint32_t)f2bf_u(acc[mt][nt][2]) << 16);
        W32[(base >> 1) + 16] =
            (uint32_t)f2bf_u(acc[mt][nt][1]) | ((uint32_t)f2bf_u(acc[mt][nt][3]) << 16);
      }
    LGKM_DRAIN();
    const int dl = lane >> 3;                 // 0..7
    const int bi = (lane >> 2) & 1;
    const int sc = (lane & 3) * 8;
    const int s0 = (row0 >> 1) + wm * 32;
    const int n = bi * NH + hd;
#pragma unroll
    for (int it = 0; it < 8; ++it) {
      int d = it * 8 + dl;
      bf16x8 vv = ldb8(W + d * 76 + bi * 32 + sc);
      *(bf16x8*)(Vtb + (size_t)(n * HN + d) * SQ + s0 + sc) = vv;
    }
  }
}

// ---------------------------------------------------------------------------
// Kernel 3: flash attention, k-split x2 in-block + LDS K/V staging
// (r6 structure, proven). Epilogue now stores ctx via plds round-trip:
// 128B-contiguous 16B/lane stores instead of 32B runs.
// ---------------------------------------------------------------------------
__global__ __launch_bounds__(512, 6) void attn_kernel(
    const uint16_t* __restrict__ Qb, const uint16_t* __restrict__ Kb,
    const uint16_t* __restrict__ Vtb, uint16_t* __restrict__ ctxb) {
  const int lane = threadIdx.x & 63;
  const int wave = threadIdx.x >> 6;        // 0..7
  const int quad = lane >> 4, l16 = lane & 15;
  const int head  = blockIdx.x;   // n = bi*16 + hd
  const int qtile = blockIdx.y;
  const int wq = wave & 3;                  // q-subtile
  const int hf = wave >> 2;                 // k-range half
  const int q0 = qtile * 64 + wq * 16;

  const uint16_t* Qh = Qb + (size_t)head * SQ * HN;
  const uint16_t* Kh = Kb + (size_t)head * SQ * HN;
  const uint16_t* Vh = Vtb + (size_t)head * HN * SQ;

  // LDS: [0,32768) staging stage[hf][kv][64][64]  (aliased by combine buf)
  //      [32768,51200) P tiles plds[8][16][72]
  __shared__ __align__(16) char smem_raw[51200];
  uint16_t (*stage)[2][64][64] = (uint16_t(*)[2][64][64])smem_raw;
  float (*cacc)[64][21]        = (float(*)[64][21])smem_raw;
  uint16_t (*plds)[16][72]     = (uint16_t(*)[16][72])(smem_raw + 32768);

  const int lr8 = lane >> 3;            // row-within-8
  const int lc8 = lane & 7;             // phys 16B chunk
  const int sc8 = (lc8 - lr8) & 7;      // logical chunk this lane fetches

  // Q fragments, persistent
  bf16x8 aq0 = ldb8(Qh + (q0 + l16) * HN + quad * 8);
  bf16x8 aq1 = ldb8(Qh + (q0 + l16) * HN + 32 + quad * 8);

  float lrun[4];
  f32x4 acc[4];
#pragma unroll
  for (int r = 0; r < 4; ++r) {
    lrun[r] = 0.f;
    acc[r] = (f32x4){0.f, 0.f, 0.f, 0.f};
  }
  const float sc2 = 0.125f * 1.44269504f;   // 1/sqrt(64) * log2(e)

  for (int kt = 0; kt < 16; ++kt) {
    const int kbase = (hf * 16 + kt) * 64;
    // --- stage K tile rows + V^T tile rows for this half (4 gll16/wave) ---
#pragma unroll
    for (int j = 0; j < 2; ++j) {
      int rr = wq * 16 + j * 8;
      gll16(Kh + (size_t)(kbase + rr + lr8) * HN + sc8 * 8, &stage[hf][0][rr][0]);
      gll16(Vh + (size_t)(rr + lr8) * SQ + kbase + sc8 * 8, &stage[hf][1][rr][0]);
    }
    __syncthreads();   // staging complete (auto vmcnt(0) before barrier)

    // --- S = Q K^T (frags straight from swizzled LDS) ---
    f32x4 s4[4];
#pragma unroll
    for (int st = 0; st < 4; ++st) {
      bf16x8 k0 = ldb8(&stage[hf][0][st * 16 + l16][0] + ((quad + l16) & 7) * 8);
      bf16x8 k1 = ldb8(&stage[hf][0][st * 16 + l16][0] + ((quad + 4 + l16) & 7) * 8);
      f32x4 z = (f32x4){0.f, 0.f, 0.f, 0.f};
      z = MFMA16(aq0, k0, z);
      s4[st] = MFMA16(aq1, k1, z);
    }
    // --- exp2-domain softmax, P -> per-wave LDS, per-lane partial sums ---
#pragma unroll
    for (int st = 0; st < 4; ++st)
#pragma unroll
      for (int r = 0; r < 4; ++r) {
        float p = __builtin_amdgcn_exp2f(s4[st][r] * sc2);
        plds[wave][quad * 4 + r][st * 16 + l16] = f2bf_u(p);
        lrun[r] += p;
      }
    LGKM_DRAIN();      // same-wave DS ordering only
    bf16x8 ap0 = ldb8(&plds[wave][l16][quad * 8]);
    bf16x8 ap1 = ldb8(&plds[wave][l16][32 + quad * 8]);
    // --- ctx += P @ V ---
#pragma unroll
    for (int dt = 0; dt < 4; ++dt) {
      bf16x8 v0 = ldb8(&stage[hf][1][dt * 16 + l16][0] + ((quad + l16) & 7) * 8);
      bf16x8 v1 = ldb8(&stage[hf][1][dt * 16 + l16][0] + ((quad + 4 + l16) & 7) * 8);
      acc[dt] = MFMA16(ap0, v0, acc[dt]);
      acc[dt] = MFMA16(ap1, v1, acc[dt]);
    }
    __syncthreads();   // all frag reads done before next staging
  }

  // --- k-split combine (linear: no max-tracking) via aliased LDS ---
  if (hf) {
    float* dst = cacc[wq][lane];
#pragma unroll
    for (int dt = 0; dt < 4; ++dt)
#pragma unroll
      for (int r = 0; r < 4; ++r) dst[dt * 4 + r] = acc[dt][r];
#pragma unroll
    for (int r = 0; r < 4; ++r) dst[16 + r] = lrun[r];
  }
  __syncthreads();
  if (hf) return;
  {
    const float* src = cacc[wq][lane];
#pragma unroll
    for (int dt = 0; dt < 4; ++dt)
#pragma unroll
      for (int r = 0; r < 4; ++r) acc[dt][r] += src[dt * 4 + r];
#pragma unroll
    for (int r = 0; r < 4; ++r) lrun[r] += src[16 + r];
  }

  // --- epilogue: row-sum reduction, normalize, coalesced store via plds ---
  float rinv[4];
#pragma unroll
  for (int r = 0; r < 4; ++r) {
    float ls = lrun[r];
    ls += __shfl_xor(ls, 1);
    ls += __shfl_xor(ls, 2);
    ls += __shfl_xor(ls, 4);
    ls += __shfl_xor(ls, 8);
    rinv[r] = __builtin_amdgcn_rcpf(ls);
  }
#pragma unroll
  for (int dt = 0; dt < 4; ++dt)
#pragma unroll
    for (int r = 0; r < 4; ++r)
      plds[wave][quad * 4 + r][dt * 16 + l16] = f2bf_u(acc[dt][r] * rinv[r]);
  LGKM_DRAIN();
  {
    const int q8 = lane >> 3, d0 = (lane & 7) * 8;
    const int gc = (head >> 1) * HN + d0;
#pragma unroll
    for (int it = 0; it < 2; ++it) {
      int ql = it * 8 + q8;
      bf16x8 vv = ldb8(&plds[wave][ql][d0]);
      int row = 2 * (q0 + ql) + (head & 1);    // reference (nh,b) view scramble
      *(bf16x8*)(ctxb + (size_t)row * H + gc) = vv;
    }
  }
}

// ---------------------------------------------------------------------------
// Kernel 4: projection + bias, m97 structure (unchanged).
// ---------------------------------------------------------------------------
__global__ __launch_bounds__(256) void gemm_proj_kernel(
    const uint16_t* __restrict__ ab, const uint16_t* __restrict__ wb,
    const float* __restrict__ bias, float* __restrict__ out) {
  const int lane = threadIdx.x & 63;
  const int wave = threadIdx.x >> 6;
  const int quad = lane >> 4, l16 = lane & 15;
  const int row0 = blockIdx.y * 128, col0 = blockIdx.x * 64;

  __shared__ __align__(16) uint16_t sA[128 * 32];
  __shared__ __align__(16) uint16_t sB[64 * 32];

  const int lrow = lane >> 2;
  const int lk   = (lane & 3) * 8;

  f32x4 acc[2][4];
#pragma unroll
  for (int i = 0; i < 2; ++i)
#pragma unroll
    for (int j = 0; j < 4; ++j) acc[i][j] = (f32x4){0.f, 0.f, 0.f, 0.f};

  for (int k0 = 0; k0 < H; k0 += 32) {
#pragma unroll
    for (int c = 0; c < 2; ++c) {
      int g = c * 4 + wave;
      gll16(ab + (size_t)(row0 + g * 16 + lrow) * H + k0 + lk, sA + g * 512);
    }
    gll16(wb + (size_t)(col0 + wave * 16 + lrow) * H + k0 + lk, sB + wave * 512);
    __syncthreads();
    bf16x8 af[2], bfr[4];
#pragma unroll
    for (int mt = 0; mt < 2; ++mt)
      af[mt] = ldb8(sA + (wave * 32 + mt * 16 + l16) * 32 + quad * 8);
#pragma unroll
    for (int nt = 0; nt < 4; ++nt)
      bfr[nt] = ldb8(sB + (nt * 16 + l16) * 32 + quad * 8);
#pragma unroll
    for (int mt = 0; mt < 2; ++mt)
#pragma unroll
      for (int nt = 0; nt < 4; ++nt)
        acc[mt][nt] = MFMA16(af[mt], bfr[nt], acc[mt][nt]);
    __syncthreads();
  }

#pragma unroll
  for (int mt = 0; mt < 2; ++mt)
#pragma unroll
    for (int nt = 0; nt < 4; ++nt)
#pragma unroll
      for (int r = 0; r < 4; ++r) {
        int m = row0 + wave * 32 + mt * 16 + quad * 4 + r;  // t' = s*2+bi
        int c = col0 + nt * 16 + l16;
        int s = m >> 1, bi = m & 1;
        out[(size_t)(bi * SQ + s) * H + c] = acc[mt][nt][r] + bias[c];
      }
}

// ---------------------------------------------------------------------------
extern "C" void kernel_launch(void* const* d_in, const int* in_sizes, int n_in,
                              void* d_out, int out_size, void* d_ws, size_t ws_size,
                              hipStream_t stream) {
  const float* x     = (const float*)d_in[0];
  const float* wqkv  = (const float*)d_in[3];
  const float* wproj = (const float*)d_in[4];
  const float* bproj = (const float*)d_in[5];
  float* out = (float*)d_out;

  char* ws = (char*)d_ws;
  uint16_t* xb     = (uint16_t*)(ws);                        //  8 MB
  uint16_t* wqkvb  = (uint16_t*)(ws + (8ull  << 20));        //  6 MB
  uint16_t* wprojb = (uint16_t*)(ws + (14ull << 20));        //  2 MB
  uint16_t* Qb     = (uint16_t*)(ws + (16ull << 20));        //  8 MB [32][2048][64]
  uint16_t* Kb     = (uint16_t*)(ws + (24ull << 20));        //  8 MB [32][2048][64]
  uint16_t* Vtb    = (uint16_t*)(ws + (32ull << 20));        //  8 MB [32][64][2048]
  uint16_t* ctxb   = (uint16_t*)(ws + (40ull << 20));        //  8 MB [4096][1024]

  convert_kernel<<<8192, 256, 0, stream>>>(x, wqkv, wproj, xb, wqkvb, wprojb);
  gemm_qkv_kernel<<<dim3(N3H / 128, T_TOK / 128), 256, 0, stream>>>(xb, wqkvb, Qb, Kb, Vtb);
  attn_kernel<<<dim3(B_ * NH, SQ / 64), 512, 0, stream>>>(Qb, Kb, Vtb, ctxb);
  gemm_proj_kernel<<<dim3(H / 64, T_TOK / 128), 256, 0, stream>>>(ctxb, wprojb, bproj, out);
}